// Round 9
// baseline (251.732 us; speedup 1.0000x reference)
//
#include <hip/hip_runtime.h>
#include <stdint.h>

#define GRIDX 200
#define NCELL (GRIDX * GRIDX * GRIDX)          // 8,000,000
#define NW32 ((NCELL + 31) / 32)               // 250,000 32-bit words
#define CIN 6
#define COUT 32
#define NOFF 27
#define BN_EPS 1e-5f
#define WPB32 1024                              // words per count/base block
#define NBLK32 ((NW32 + WPB32 - 1) / WPB32)     // 245 (<=256 for single-block scan)

typedef __attribute__((ext_vector_type(8))) short short8;
typedef __attribute__((ext_vector_type(4))) float f32x4;

// ---------------- helpers ----------------

__device__ __forceinline__ int xcd_swizzle(int b, int nwg) {
    int q = nwg >> 3, r = nwg & 7;
    int xcd = b & 7, idx = b >> 3;
    int base = (xcd < r) ? xcd * (q + 1) : r * (q + 1) + (xcd - r) * q;
    return base + idx;
}

__device__ __forceinline__ unsigned short f2bf(float f) {
    uint32_t u = __float_as_uint(f);
    return (unsigned short)((u + 0x7FFFu + ((u >> 16) & 1u)) >> 16);   // RNE
}
__device__ __forceinline__ uint32_t pack2(float a, float b) {
    return (uint32_t)f2bf(a) | ((uint32_t)f2bf(b) << 16);
}
__device__ __forceinline__ float bflo(uint32_t u) { return __uint_as_float(u << 16); }
__device__ __forceinline__ float bfhi(uint32_t u) { return __uint_as_float(u & 0xFFFF0000u); }

// ---------------- 32-bit bitmap rank structure ----------------

__global__ void build_bitmap32(const int* __restrict__ coords, int N,
                               uint32_t* __restrict__ words) {
    int i = blockIdx.x * blockDim.x + threadIdx.x;
    if (i >= N) return;
    int x = coords[3 * i], y = coords[3 * i + 1], z = coords[3 * i + 2];
    int key = (x * GRIDX + y) * GRIDX + z;
    atomicOr(&words[key >> 5], 1u << (key & 31));
}

__global__ __launch_bounds__(256)
void bitmap_count32(const uint32_t* __restrict__ words, int* __restrict__ bcnt) {
    __shared__ int tot[256];
    int b = blockIdx.x, t = threadIdx.x;
    int w0 = b * WPB32 + t * 4;
    int s = 0;
#pragma unroll
    for (int j = 0; j < 4; j++) {
        int w = w0 + j;
        if (w < NW32) s += __popc(words[w]);
    }
    tot[t] = s;
    __syncthreads();
    if (t < 128) tot[t] += tot[t + 128];
    __syncthreads();
    if (t < 64) {
        int v = tot[t] + tot[t + 64];
#pragma unroll
        for (int d = 32; d > 0; d >>= 1) v += __shfl_down(v, d);
        if (t == 0) bcnt[b] = v;
    }
}

// exclusive scan of n<=256 values, one block of 256 threads
__global__ void scan_small(const int* __restrict__ cnt, int* __restrict__ base, int n) {
    __shared__ int tot[256];
    int t = threadIdx.x;
    int v = (t < n) ? cnt[t] : 0;
    tot[t] = v;
    __syncthreads();
    for (int d = 1; d < 256; d <<= 1) {
        int u = (t >= d) ? tot[t - d] : 0;
        __syncthreads();
        tot[t] += u;
        __syncthreads();
    }
    if (t < n) base[t] = tot[t] - v;     // exclusive
}

__global__ __launch_bounds__(256)
void base_fill32(const uint32_t* __restrict__ words, const int* __restrict__ bbase,
                 uint32_t* __restrict__ bases) {
    __shared__ int tot[256];
    int b = blockIdx.x, t = threadIdx.x;
    int w0 = b * WPB32 + t * 4;
    int p[4];
    int s = 0;
#pragma unroll
    for (int j = 0; j < 4; j++) {
        int w = w0 + j;
        p[j] = (w < NW32) ? __popc(words[w]) : 0;
        s += p[j];
    }
    tot[t] = s;
    __syncthreads();
    for (int d = 1; d < 256; d <<= 1) {
        int u = (t >= d) ? tot[t - d] : 0;
        __syncthreads();
        tot[t] += u;
        __syncthreads();
    }
    int run = bbase[b] + tot[t] - s;     // exclusive global rank of first word
#pragma unroll
    for (int j = 0; j < 4; j++) {
        int w = w0 + j;
        if (w < NW32) bases[w] = (uint32_t)run;
        run += p[j];
    }
}

// ---------------- rank scatter: original order -> sorted order ----------------

template <bool WRITE_SORIG>
__global__ __launch_bounds__(256)
void rank_scatter32(const int* __restrict__ coords, const float* __restrict__ feat, int N,
                    const uint32_t* __restrict__ words, const uint32_t* __restrict__ bases,
                    int* __restrict__ sorig, int* __restrict__ rorig,
                    int* __restrict__ skeys, uint4* __restrict__ feat_bf) {
    int i = blockIdx.x * blockDim.x + threadIdx.x;
    if (i >= N) return;
    int x = coords[3 * i], y = coords[3 * i + 1], z = coords[3 * i + 2];
    int key = (x * GRIDX + y) * GRIDX + z;
    int wi = key >> 5;
    int bit = key & 31;
    uint32_t wd = words[wi];
    int r = (int)(bases[wi] + (uint32_t)__popc(wd & ((1u << bit) - 1u)));
    if (WRITE_SORIG) sorig[r] = i;       // tier2: scatter
    else             rorig[i] = r;       // tier1: sequential
    skeys[r] = key;
    const float* fr = feat + (size_t)i * CIN;
    float2 a = *(const float2*)fr;
    float2 bb = *(const float2*)(fr + 2);
    float2 cc = *(const float2*)(fr + 4);
    uint4 u;
    u.x = pack2(a.x, a.y);
    u.y = pack2(bb.x, bb.y);
    u.z = pack2(cc.x, cc.y);
    u.w = 0u;
    feat_bf[r] = u;
}

// ---------------- W fragment prep (once) ----------------
// K-packing: k = koff*8 + ci (ci<6 real, ci=6,7 zero; koff>=27 zero).
// B-fragment (16x16x32 bf16): lane l holds B[k = ks*32+(l>>4)*8+b][col = nt*16+(l&15)]

__global__ void prep_wfrag(const float* __restrict__ W, uint4* __restrict__ wfrag) {
    int idx = blockIdx.x * blockDim.x + threadIdx.x;
    if (idx >= 7 * 2 * 64) return;
    int l = idx & 63;
    int nt = (idx >> 6) & 1;
    int ks = idx >> 7;
    int koff = ks * 4 + (l >> 4);
    int col = nt * 16 + (l & 15);
    unsigned short v[8];
#pragma unroll
    for (int ci = 0; ci < 8; ci++) {
        float f = 0.f;
        if (ci < CIN && koff < NOFF) f = W[(koff * CIN + ci) * COUT + col];
        v[ci] = f2bf(f);
    }
    uint4 u;
    u.x = (uint32_t)v[0] | ((uint32_t)v[1] << 16);
    u.y = (uint32_t)v[2] | ((uint32_t)v[3] << 16);
    u.z = (uint32_t)v[4] | ((uint32_t)v[5] << 16);
    u.w = (uint32_t)v[6] | ((uint32_t)v[7] << 16);
    wfrag[idx] = u;
}

// ---------------- shared conv body (gather + MFMA + stats + LDS transpose) ----------------

__device__ __forceinline__ void conv_core(const uint4* __restrict__ feat_bf,
                                          const int* __restrict__ skeys,
                                          const uint4* __restrict__ wfrag,
                                          const uint32_t* __restrict__ words,
                                          const uint32_t* __restrict__ bases, int N,
                                          float* __restrict__ stats_g,
                                          float* Clds, float* bstat,
                                          int tid, int blkid, int nblk) {
    int w = tid >> 6, l = tid & 63;

    if (tid < 64) bstat[tid] = 0.f;
    __syncthreads();

    const short8* wf8 = (const short8*)wfrag;
    short8 bf0[7], bf1[7];
#pragma unroll
    for (int ks = 0; ks < 7; ks++) {
        bf0[ks] = wf8[(ks * 2 + 0) * 64 + l];
        bf1[ks] = wf8[(ks * 2 + 1) * 64 + l];
    }

    int b = xcd_swizzle(blkid, nblk);
    int bs = b * 64;
    int site = bs + w * 16 + (l & 15);
    bool sv = (site < N);
    int key = sv ? skeys[site] : 0;
    int x = key / (GRIDX * GRIDX);
    int rem = key % (GRIDX * GRIDX);
    int y = rem / GRIDX;
    int z = rem % GRIDX;
    int kb = l >> 4;

    f32x4 acc0 = {0.f, 0.f, 0.f, 0.f};
    f32x4 acc1 = {0.f, 0.f, 0.f, 0.f};
    const short8* fb8 = (const short8*)feat_bf;

#pragma unroll
    for (int ks = 0; ks < 7; ks++) {
        int koff = ks * 4 + kb;          // 0..27 (27 = zero-pad)
        int t9 = koff / 9;
        int r9 = koff - t9 * 9;
        int t3 = r9 / 3;
        int dx = t9 - 1, dy = t3 - 1, dz = r9 - t3 * 3 - 1;
        int nx = x + dx, ny = y + dy, nz = z + dz;
        bool ok = sv && (koff < NOFF) &&
                  ((unsigned)nx < GRIDX) && ((unsigned)ny < GRIDX) && ((unsigned)nz < GRIDX);
        int nkey = key + dx * (GRIDX * GRIDX) + dy * GRIDX + dz;
        nkey = min(max(nkey, 0), NCELL - 1);
        int wi = nkey >> 5;
        int bit = nkey & 31;
        uint32_t wd = words[wi];
        uint32_t bb = bases[wi];
        bool hit = ok && ((wd >> bit) & 1u);
        int pos = hit ? (int)(bb + (uint32_t)__popc(wd & ((1u << bit) - 1u))) : N;
        short8 a = fb8[pos];
        acc0 = __builtin_amdgcn_mfma_f32_16x16x32_bf16(a, bf0[ks], acc0, 0, 0, 0);
        acc1 = __builtin_amdgcn_mfma_f32_16x16x32_bf16(a, bf1[ks], acc1, 0, 0, 0);
    }

    int col = l & 15;
    int rg = l >> 4;

    // C transpose staging
#pragma unroll
    for (int r = 0; r < 4; r++) {
        int s = w * 16 + rg * 4 + r;     // C/D map: col=lane&15, row=(lane>>4)*4+r
        Clds[s * 36 + col] = acc0[r];
        Clds[s * 36 + col + 16] = acc1[r];
    }

    // fused BN stats (pre-norm, f32 exact); invalid sites contribute zeros
    float s0 = acc0[0] + acc0[1] + acc0[2] + acc0[3];
    float q0 = acc0[0]*acc0[0] + acc0[1]*acc0[1] + acc0[2]*acc0[2] + acc0[3]*acc0[3];
    float s1 = acc1[0] + acc1[1] + acc1[2] + acc1[3];
    float q1 = acc1[0]*acc1[0] + acc1[1]*acc1[1] + acc1[2]*acc1[2] + acc1[3]*acc1[3];
    s0 += __shfl_xor(s0, 16); s0 += __shfl_xor(s0, 32);
    q0 += __shfl_xor(q0, 16); q0 += __shfl_xor(q0, 32);
    s1 += __shfl_xor(s1, 16); s1 += __shfl_xor(s1, 32);
    q1 += __shfl_xor(q1, 16); q1 += __shfl_xor(q1, 32);
    if (l < 16) {
        atomicAdd(&bstat[col], s0);
        atomicAdd(&bstat[16 + col], s1);
        atomicAdd(&bstat[32 + col], q0);
        atomicAdd(&bstat[48 + col], q1);
    }
    __syncthreads();                     // Clds writes + bstat complete

    if (tid < 64) {
        int slice = blkid & 63;
        atomicAdd(&stats_g[slice * 64 + tid], bstat[tid]);
    }
}

// ---------------- tier1 conv: coalesced bf16 ws writes ----------------

__global__ __launch_bounds__(256, 8)
void conv_mfma_ws(const uint4* __restrict__ feat_bf,
                  const int* __restrict__ skeys,
                  const uint4* __restrict__ wfrag,
                  const uint32_t* __restrict__ words,
                  const uint32_t* __restrict__ bases, int N,
                  uint4* __restrict__ wsacc,          // N rows x 64B (bf16x32)
                  float* __restrict__ stats_g) {
    __shared__ __align__(16) float Clds[64 * 36];
    __shared__ float bstat[64];
    int tid = threadIdx.x;
    conv_core(feat_bf, skeys, wfrag, words, bases, N, stats_g,
              Clds, bstat, tid, blockIdx.x, gridDim.x);

    int b = xcd_swizzle(blockIdx.x, gridDim.x);
    int bs = b * 64;
    int st = tid >> 2;
    int q = tid & 3;
    int sr = bs + st;
    if (sr < N) {
        const float* cp = &Clds[st * 36 + q * 8];
        uint4 v;
        v.x = pack2(cp[0], cp[1]);
        v.y = pack2(cp[2], cp[3]);
        v.z = pack2(cp[4], cp[5]);
        v.w = pack2(cp[6], cp[7]);
        wsacc[(size_t)sr * 4 + q] = v;   // contiguous 4KB per block
    }
}

// ---------------- tier2 conv (R8): scattered f32 out writes ----------------

__global__ __launch_bounds__(256, 4)
void conv_mfma_scat(const uint4* __restrict__ feat_bf,
                    const int* __restrict__ skeys,
                    const int* __restrict__ sorig,
                    const uint4* __restrict__ wfrag,
                    const uint32_t* __restrict__ words,
                    const uint32_t* __restrict__ bases, int N,
                    float* __restrict__ out,
                    float* __restrict__ stats_g) {
    __shared__ __align__(16) float Clds[64 * 36];
    __shared__ float bstat[64];
    int tid = threadIdx.x;
    conv_core(feat_bf, skeys, wfrag, words, bases, N, stats_g,
              Clds, bstat, tid, blockIdx.x, gridDim.x);

    int b = xcd_swizzle(blockIdx.x, gridDim.x);
    int bs = b * 64;
    int st = tid >> 2;
    int q = (tid & 3) * 2;
    int sr = bs + st;
    if (sr < N) {
        float4* gp = (float4*)(out + (size_t)sorig[sr] * COUT + q * 4);
        gp[0] = *(const float4*)&Clds[st * 36 + q * 4];
        gp[1] = *(const float4*)&Clds[st * 36 + q * 4 + 4];
    }
}

// ---------------- BN finalize ----------------

__global__ void finalize_sliced(const float* __restrict__ stats_g,
                                const float* __restrict__ gamma,
                                const float* __restrict__ beta,
                                float invN, float* __restrict__ scsh) {
    int c = threadIdx.x;
    if (c < COUT) {
        float s = 0.f, q = 0.f;
        for (int sl = 0; sl < 64; sl++) {
            s += stats_g[sl * 64 + c];
            q += stats_g[sl * 64 + 32 + c];
        }
        float mean = s * invN;
        float var = q * invN - mean * mean;
        float sc = gamma[c] * rsqrtf(var + BN_EPS);
        scsh[c] = sc;
        scsh[COUT + c] = beta[c] - mean * sc;
    }
}

// ---------------- tier1 norm: gather sorted ws, write out coalesced ----------------

__global__ __launch_bounds__(256)
void norm_gather(const uint4* __restrict__ wsacc, const int* __restrict__ rorig,
                 int N, const float* __restrict__ scsh, float* __restrict__ out) {
    __shared__ float sc[COUT], sh[COUT];
    for (int t = threadIdx.x; t < COUT; t += blockDim.x) {
        sc[t] = scsh[t];
        sh[t] = scsh[COUT + t];
    }
    __syncthreads();
    int tid = blockIdx.x * blockDim.x + threadIdx.x;
    int i = tid >> 2, q = tid & 3;
    if (i >= N) return;
    int r = rorig[i];                    // sequential 4B read
    uint4 v = wsacc[(size_t)r * 4 + q];  // 16B of a 64B L3-resident row
    int cb = q * 8;
    float4 o0, o1;
    o0.x = fmaxf(bflo(v.x) * sc[cb + 0] + sh[cb + 0], 0.f);
    o0.y = fmaxf(bfhi(v.x) * sc[cb + 1] + sh[cb + 1], 0.f);
    o0.z = fmaxf(bflo(v.y) * sc[cb + 2] + sh[cb + 2], 0.f);
    o0.w = fmaxf(bfhi(v.y) * sc[cb + 3] + sh[cb + 3], 0.f);
    o1.x = fmaxf(bflo(v.z) * sc[cb + 4] + sh[cb + 4], 0.f);
    o1.y = fmaxf(bfhi(v.z) * sc[cb + 5] + sh[cb + 5], 0.f);
    o1.z = fmaxf(bflo(v.w) * sc[cb + 6] + sh[cb + 6], 0.f);
    o1.w = fmaxf(bfhi(v.w) * sc[cb + 7] + sh[cb + 7], 0.f);
    float4* gp = (float4*)(out + (size_t)i * COUT + cb);
    gp[0] = o0;                          // coalesced across tid
    gp[1] = o1;
}

// ---------------- tier2 norm (R8): in-place sequential ----------------

__global__ __launch_bounds__(256)
void norm_kernel(float* __restrict__ out, long total_vec,
                 const float* __restrict__ scaleshift) {
    __shared__ float sc[COUT], sh[COUT];
    for (int t = threadIdx.x; t < COUT; t += blockDim.x) {
        sc[t] = scaleshift[t];
        sh[t] = scaleshift[COUT + t];
    }
    __syncthreads();
    long stride = (long)gridDim.x * blockDim.x;
    float4* p = (float4*)out;
    for (long v = (long)blockIdx.x * blockDim.x + threadIdx.x; v < total_vec; v += stride) {
        int cbase = (int)(v & 7) * 4;
        float4 u = p[v];
        u.x = fmaxf(u.x * sc[cbase + 0] + sh[cbase + 0], 0.f);
        u.y = fmaxf(u.y * sc[cbase + 1] + sh[cbase + 1], 0.f);
        u.z = fmaxf(u.z * sc[cbase + 2] + sh[cbase + 2], 0.f);
        u.w = fmaxf(u.w * sc[cbase + 3] + sh[cbase + 3], 0.f);
        p[v] = u;
    }
}

// ---------------- launch ----------------

extern "C" void kernel_launch(void* const* d_in, const int* in_sizes, int n_in,
                              void* d_out, int out_size, void* d_ws, size_t ws_size,
                              hipStream_t stream) {
    const float* feat   = (const float*)d_in[0];
    const int*   coords = (const int*)d_in[1];
    const float* W      = (const float*)d_in[2];
    const float* gamma  = (const float*)d_in[3];
    const float* beta   = (const float*)d_in[4];
    float* out = (float*)d_out;

    int N = in_sizes[0] / CIN;
    const int threads = 256;
    int blocksN = (N + threads - 1) / threads;
    int cblocks = (N + 63) / 64;
    long total_vec = (long)N * COUT / 4;

    size_t a256 = 255;
    size_t words_b    = (size_t)NW32 * 4;                      // 1 MB
    size_t off_bases  = (words_b + a256) & ~a256;
    size_t off_skeys  = (off_bases + (size_t)NW32 * 4 + a256) & ~a256;
    size_t off_featbf = (off_skeys + (size_t)N * 4 + a256) & ~a256;
    size_t off_bcnt   = (off_featbf + (size_t)(N + 1) * 16 + a256) & ~a256;
    size_t off_bbase  = (off_bcnt + 256 * 4 + a256) & ~a256;
    size_t off_wfrag  = (off_bbase + 256 * 4 + a256) & ~a256;
    size_t off_stats  = (off_wfrag + (size_t)(7 * 2 * 64) * 16 + a256) & ~a256;
    size_t off_scsh   = off_stats + (size_t)64 * 64 * 4;
    size_t off_common = off_scsh + 2 * COUT * sizeof(float);
    size_t off_rorig  = (off_common + a256) & ~a256;           // tier1
    size_t off_wsacc  = (off_rorig + (size_t)N * 4 + a256) & ~a256;
    size_t need_t1    = off_wsacc + (size_t)N * 64 + 256;
    size_t off_sorig  = (off_common + a256) & ~a256;           // tier2
    size_t need_t2    = off_sorig + (size_t)N * 4 + 256;

    uint32_t* words = (uint32_t*)d_ws;
    uint32_t* bases = (uint32_t*)((char*)d_ws + off_bases);
    int*   skeys = (int*)((char*)d_ws + off_skeys);
    uint4* featb = (uint4*)((char*)d_ws + off_featbf);
    int*   bcnt  = (int*)((char*)d_ws + off_bcnt);
    int*   bbase = (int*)((char*)d_ws + off_bbase);
    uint4* wfrag = (uint4*)((char*)d_ws + off_wfrag);
    float* stats = (float*)((char*)d_ws + off_stats);
    float* scsh  = (float*)((char*)d_ws + off_scsh);

    if (ws_size >= need_t1) {
        int*   rorig = (int*)((char*)d_ws + off_rorig);
        uint4* wsacc = (uint4*)((char*)d_ws + off_wsacc);

        hipMemsetAsync(words, 0, words_b, stream);
        hipMemsetAsync(featb + N, 0, 16, stream);              // zero row
        hipMemsetAsync(stats, 0, (size_t)64 * 64 * 4, stream);
        prep_wfrag<<<4, threads, 0, stream>>>(W, wfrag);
        build_bitmap32<<<blocksN, threads, 0, stream>>>(coords, N, words);
        bitmap_count32<<<NBLK32, threads, 0, stream>>>(words, bcnt);
        scan_small<<<1, threads, 0, stream>>>(bcnt, bbase, NBLK32);
        base_fill32<<<NBLK32, threads, 0, stream>>>(words, bbase, bases);
        rank_scatter32<false><<<blocksN, threads, 0, stream>>>(coords, feat, N, words, bases,
                                                               nullptr, rorig, skeys, featb);
        conv_mfma_ws<<<cblocks, threads, 0, stream>>>(featb, skeys, wfrag,
                                                      words, bases, N, wsacc, stats);
        finalize_sliced<<<1, 64, 0, stream>>>(stats, gamma, beta, 1.0f / (float)N, scsh);
        int nblocks = (4 * N + threads - 1) / threads;
        norm_gather<<<nblocks, threads, 0, stream>>>(wsacc, rorig, N, scsh, out);
        return;
    }

    if (ws_size >= need_t2) {
        int* sorig = (int*)((char*)d_ws + off_sorig);

        hipMemsetAsync(words, 0, words_b, stream);
        hipMemsetAsync(featb + N, 0, 16, stream);
        hipMemsetAsync(stats, 0, (size_t)64 * 64 * 4, stream);
        prep_wfrag<<<4, threads, 0, stream>>>(W, wfrag);
        build_bitmap32<<<blocksN, threads, 0, stream>>>(coords, N, words);
        bitmap_count32<<<NBLK32, threads, 0, stream>>>(words, bcnt);
        scan_small<<<1, threads, 0, stream>>>(bcnt, bbase, NBLK32);
        base_fill32<<<NBLK32, threads, 0, stream>>>(words, bbase, bases);
        rank_scatter32<true><<<blocksN, threads, 0, stream>>>(coords, feat, N, words, bases,
                                                              sorig, nullptr, skeys, featb);
        conv_mfma_scat<<<cblocks, threads, 0, stream>>>(featb, skeys, sorig, wfrag,
                                                        words, bases, N, out, stats);
        finalize_sliced<<<1, 64, 0, stream>>>(stats, gamma, beta, 1.0f / (float)N, scsh);
        norm_kernel<<<2048, threads, 0, stream>>>(out, total_vec, scsh);
        return;
    }
}

// Round 10
// 241.874 us; speedup vs baseline: 1.0408x; 1.0408x over previous
//
#include <hip/hip_runtime.h>
#include <stdint.h>

#define GRIDX 200
#define P 202                                   // padded grid dim
#define PCELL (P * P * P)                       // 8,242,408
#define GUARD 100000
#define NBITS (PCELL + GUARD)
#define NWP ((NBITS + 31) / 32)                 // 260,701 words
#define K_INV (PCELL + 50000)                   // guaranteed-miss key (guard center)
#define CIN 6
#define COUT 32
#define NOFF 27
#define BN_EPS 1e-5f
#define WPB 1024
#define NBLKP ((NWP + WPB - 1) / WPB)           // 255 (<=256 for single-block scan)

typedef __attribute__((ext_vector_type(8))) short short8;
typedef __attribute__((ext_vector_type(4))) float f32x4;

// ---------------- helpers ----------------

__device__ __forceinline__ int xcd_swizzle(int b, int nwg) {
    int q = nwg >> 3, r = nwg & 7;
    int xcd = b & 7, idx = b >> 3;
    int base = (xcd < r) ? xcd * (q + 1) : r * (q + 1) + (xcd - r) * q;
    return base + idx;
}

__device__ __forceinline__ unsigned short f2bf(float f) {
    uint32_t u = __float_as_uint(f);
    return (unsigned short)((u + 0x7FFFu + ((u >> 16) & 1u)) >> 16);   // RNE
}
__device__ __forceinline__ uint32_t pack2(float a, float b) {
    return (uint32_t)f2bf(a) | ((uint32_t)f2bf(b) << 16);
}

// ---------------- padded bitmap rank structure (uint2 = {word, base}) ----------------

__global__ void build_bitmap_p(const int* __restrict__ coords, int N,
                               uint2* __restrict__ recs) {
    int i = blockIdx.x * blockDim.x + threadIdx.x;
    if (i >= N) return;
    int x = coords[3 * i], y = coords[3 * i + 1], z = coords[3 * i + 2];
    int key = ((x + 1) * P + (y + 1)) * P + (z + 1);
    atomicOr((unsigned int*)&recs[key >> 5], 1u << (key & 31));
}

__global__ __launch_bounds__(256)
void bitmap_count_p(const uint2* __restrict__ recs, int* __restrict__ bcnt) {
    __shared__ int tot[256];
    int b = blockIdx.x, t = threadIdx.x;
    int w0 = b * WPB + t * 4;
    int s = 0;
#pragma unroll
    for (int j = 0; j < 4; j++) {
        int w = w0 + j;
        if (w < NWP) s += __popc(recs[w].x);
    }
    tot[t] = s;
    __syncthreads();
    if (t < 128) tot[t] += tot[t + 128];
    __syncthreads();
    if (t < 64) {
        int v = tot[t] + tot[t + 64];
#pragma unroll
        for (int d = 32; d > 0; d >>= 1) v += __shfl_down(v, d);
        if (t == 0) bcnt[b] = v;
    }
}

// exclusive scan of n<=256 values, one block of 256 threads
__global__ void scan_small(const int* __restrict__ cnt, int* __restrict__ base, int n) {
    __shared__ int tot[256];
    int t = threadIdx.x;
    int v = (t < n) ? cnt[t] : 0;
    tot[t] = v;
    __syncthreads();
    for (int d = 1; d < 256; d <<= 1) {
        int u = (t >= d) ? tot[t - d] : 0;
        __syncthreads();
        tot[t] += u;
        __syncthreads();
    }
    if (t < n) base[t] = tot[t] - v;     // exclusive
}

__global__ __launch_bounds__(256)
void base_fill_p(uint2* __restrict__ recs, const int* __restrict__ bbase) {
    __shared__ int tot[256];
    int b = blockIdx.x, t = threadIdx.x;
    int w0 = b * WPB + t * 4;
    int p[4];
    int s = 0;
#pragma unroll
    for (int j = 0; j < 4; j++) {
        int w = w0 + j;
        p[j] = (w < NWP) ? __popc(recs[w].x) : 0;
        s += p[j];
    }
    tot[t] = s;
    __syncthreads();
    for (int d = 1; d < 256; d <<= 1) {
        int u = (t >= d) ? tot[t - d] : 0;
        __syncthreads();
        tot[t] += u;
        __syncthreads();
    }
    int run = bbase[b] + tot[t] - s;     // exclusive global rank of first word
#pragma unroll
    for (int j = 0; j < 4; j++) {
        int w = w0 + j;
        if (w < NWP) recs[w].y = (uint32_t)run;
        run += p[j];
    }
}

// ---------------- rank scatter: original order -> sorted order ----------------

__global__ __launch_bounds__(256)
void rank_scatter_p(const int* __restrict__ coords, const float* __restrict__ feat, int N,
                    const uint2* __restrict__ recs,
                    int* __restrict__ sorig, int* __restrict__ skeys,
                    uint4* __restrict__ feat_bf) {
    int i = blockIdx.x * blockDim.x + threadIdx.x;
    if (i >= N) return;
    int x = coords[3 * i], y = coords[3 * i + 1], z = coords[3 * i + 2];
    int key = ((x + 1) * P + (y + 1)) * P + (z + 1);
    uint2 rb = recs[key >> 5];
    int bit = key & 31;
    int r = (int)(rb.y + (uint32_t)__popc(rb.x & ((1u << bit) - 1u)));
    sorig[r] = i;
    skeys[r] = key;
    const float* fr = feat + (size_t)i * CIN;
    float2 a = *(const float2*)fr;
    float2 bb = *(const float2*)(fr + 2);
    float2 cc = *(const float2*)(fr + 4);
    uint4 u;
    u.x = pack2(a.x, a.y);
    u.y = pack2(bb.x, bb.y);
    u.z = pack2(cc.x, cc.y);
    u.w = 0u;
    feat_bf[r] = u;
}

// ---------------- W fragment prep (once) ----------------
// K-packing: k = koff*8 + ci (ci<6 real, ci=6,7 zero; koff>=27 zero).
// B-fragment (16x16x32 bf16): lane l holds B[k = ks*32+(l>>4)*8+b][col = nt*16+(l&15)]

__global__ void prep_wfrag(const float* __restrict__ W, uint4* __restrict__ wfrag) {
    int idx = blockIdx.x * blockDim.x + threadIdx.x;
    if (idx >= 7 * 2 * 64) return;
    int l = idx & 63;
    int nt = (idx >> 6) & 1;
    int ks = idx >> 7;
    int koff = ks * 4 + (l >> 4);
    int col = nt * 16 + (l & 15);
    unsigned short v[8];
#pragma unroll
    for (int ci = 0; ci < 8; ci++) {
        float f = 0.f;
        if (ci < CIN && koff < NOFF) f = W[(koff * CIN + ci) * COUT + col];
        v[ci] = f2bf(f);
    }
    uint4 u;
    u.x = (uint32_t)v[0] | ((uint32_t)v[1] << 16);
    u.y = (uint32_t)v[2] | ((uint32_t)v[3] << 16);
    u.z = (uint32_t)v[4] | ((uint32_t)v[5] << 16);
    u.w = (uint32_t)v[6] | ((uint32_t)v[7] << 16);
    wfrag[idx] = u;
}

// ---------------- conv: batched register gather -> MFMA, fused stats ----------------
// Padded-grid probes: no bounds checks (border cells never set); invalid sites and
// the koff=27 pad slot probe K_INV inside the zeroed guard band -> guaranteed miss.

__global__ __launch_bounds__(256, 4)
void conv_mfma(const uint4* __restrict__ feat_bf,      // N+1 rows (row N = zeros)
               const int* __restrict__ skeys,
               const int* __restrict__ sorig,
               const uint4* __restrict__ wfrag,
               const uint2* __restrict__ recs, int N,
               float* __restrict__ out,
               float* __restrict__ stats_g) {
    __shared__ __align__(16) float Clds[64 * 36];    // 9216 B
    __shared__ float bstat[64];

    int tid = threadIdx.x;
    int w = tid >> 6, l = tid & 63;

    if (tid < 64) bstat[tid] = 0.f;
    __syncthreads();

    const short8* wf8 = (const short8*)wfrag;
    short8 bf0[7], bf1[7];
#pragma unroll
    for (int ks = 0; ks < 7; ks++) {
        bf0[ks] = wf8[(ks * 2 + 0) * 64 + l];
        bf1[ks] = wf8[(ks * 2 + 1) * 64 + l];
    }

    int b = xcd_swizzle(blockIdx.x, gridDim.x);
    int bs = b * 64;
    int site = bs + w * 16 + (l & 15);
    int key = (site < N) ? skeys[site] : K_INV;
    int kb = l >> 4;

    // per-thread key deltas (once): koff = ks*4 + kb
    int dlt[7];
#pragma unroll
    for (int ks = 0; ks < 7; ks++) {
        int koff = ks * 4 + kb;
        if (koff < NOFF) {
            int t9 = koff / 9;
            int r9 = koff - t9 * 9;
            int t3 = r9 / 3;
            dlt[ks] = (t9 - 1) * (P * P) + (t3 - 1) * P + (r9 - t3 * 3 - 1);
        } else {
            dlt[ks] = K_INV - key;       // pad slot -> probe K_INV (miss)
        }
    }

    const short8* fb8 = (const short8*)feat_bf;

    // batched: all 7 rank lookups + gathers in flight, then the MFMA chain
    short8 av[7];
#pragma unroll
    for (int ks = 0; ks < 7; ks++) {
        int nkey = key + dlt[ks];
        uint2 rb = recs[nkey >> 5];      // one 8B load: {word, base}
        int bit = nkey & 31;
        bool hit = (rb.x >> bit) & 1u;
        int pos = hit ? (int)(rb.y + (uint32_t)__popc(rb.x & ((1u << bit) - 1u))) : N;
        av[ks] = fb8[pos];
    }

    f32x4 acc0 = {0.f, 0.f, 0.f, 0.f};
    f32x4 acc1 = {0.f, 0.f, 0.f, 0.f};
#pragma unroll
    for (int ks = 0; ks < 7; ks++) {
        acc0 = __builtin_amdgcn_mfma_f32_16x16x32_bf16(av[ks], bf0[ks], acc0, 0, 0, 0);
        acc1 = __builtin_amdgcn_mfma_f32_16x16x32_bf16(av[ks], bf1[ks], acc1, 0, 0, 0);
    }

    int col = l & 15;
    int rg = l >> 4;

    // C transpose staging
#pragma unroll
    for (int r = 0; r < 4; r++) {
        int s = w * 16 + rg * 4 + r;     // C/D map: col=lane&15, row=(lane>>4)*4+r
        Clds[s * 36 + col] = acc0[r];
        Clds[s * 36 + col + 16] = acc1[r];
    }

    // fused BN stats (pre-norm, f32 exact); invalid sites contribute zeros
    float s0 = acc0[0] + acc0[1] + acc0[2] + acc0[3];
    float q0 = acc0[0]*acc0[0] + acc0[1]*acc0[1] + acc0[2]*acc0[2] + acc0[3]*acc0[3];
    float s1 = acc1[0] + acc1[1] + acc1[2] + acc1[3];
    float q1 = acc1[0]*acc1[0] + acc1[1]*acc1[1] + acc1[2]*acc1[2] + acc1[3]*acc1[3];
    s0 += __shfl_xor(s0, 16); s0 += __shfl_xor(s0, 32);
    q0 += __shfl_xor(q0, 16); q0 += __shfl_xor(q0, 32);
    s1 += __shfl_xor(s1, 16); s1 += __shfl_xor(s1, 32);
    q1 += __shfl_xor(q1, 16); q1 += __shfl_xor(q1, 32);
    if (l < 16) {
        atomicAdd(&bstat[col], s0);
        atomicAdd(&bstat[16 + col], s1);
        atomicAdd(&bstat[32 + col], q0);
        atomicAdd(&bstat[48 + col], q1);
    }
    __syncthreads();                     // Clds writes + bstat complete

    if (tid < 64) {
        int slice = blockIdx.x & 63;
        atomicAdd(&stats_g[slice * 64 + tid], bstat[tid]);
    }

    int st = tid >> 2;                   // site-local 0..63
    int q = (tid & 3) * 2;               // chunk pair
    int sr = bs + st;
    if (sr < N) {
        float4* gp = (float4*)(out + (size_t)sorig[sr] * COUT + q * 4);
        gp[0] = *(const float4*)&Clds[st * 36 + q * 4];
        gp[1] = *(const float4*)&Clds[st * 36 + q * 4 + 4];
    }
}

// ---------------- BN finalize / norm ----------------

__global__ void finalize_sliced(const float* __restrict__ stats_g,
                                const float* __restrict__ gamma,
                                const float* __restrict__ beta,
                                float invN, float* __restrict__ scsh) {
    int c = threadIdx.x;
    if (c < COUT) {
        float s = 0.f, q = 0.f;
        for (int sl = 0; sl < 64; sl++) {
            s += stats_g[sl * 64 + c];
            q += stats_g[sl * 64 + 32 + c];
        }
        float mean = s * invN;
        float var = q * invN - mean * mean;
        float sc = gamma[c] * rsqrtf(var + BN_EPS);
        scsh[c] = sc;
        scsh[COUT + c] = beta[c] - mean * sc;
    }
}

__global__ __launch_bounds__(256)
void norm_kernel(float* __restrict__ out, long total_vec,
                 const float* __restrict__ scaleshift) {
    __shared__ float sc[COUT], sh[COUT];
    for (int t = threadIdx.x; t < COUT; t += blockDim.x) {
        sc[t] = scaleshift[t];
        sh[t] = scaleshift[COUT + t];
    }
    __syncthreads();
    long stride = (long)gridDim.x * blockDim.x;
    float4* p = (float4*)out;
    for (long v = (long)blockIdx.x * blockDim.x + threadIdx.x; v < total_vec; v += stride) {
        int cbase = (int)(v & 7) * 4;
        float4 u = p[v];
        u.x = fmaxf(u.x * sc[cbase + 0] + sh[cbase + 0], 0.f);
        u.y = fmaxf(u.y * sc[cbase + 1] + sh[cbase + 1], 0.f);
        u.z = fmaxf(u.z * sc[cbase + 2] + sh[cbase + 2], 0.f);
        u.w = fmaxf(u.w * sc[cbase + 3] + sh[cbase + 3], 0.f);
        p[v] = u;
    }
}

// ---------------- launch ----------------

extern "C" void kernel_launch(void* const* d_in, const int* in_sizes, int n_in,
                              void* d_out, int out_size, void* d_ws, size_t ws_size,
                              hipStream_t stream) {
    const float* feat   = (const float*)d_in[0];
    const int*   coords = (const int*)d_in[1];
    const float* W      = (const float*)d_in[2];
    const float* gamma  = (const float*)d_in[3];
    const float* beta   = (const float*)d_in[4];
    float* out = (float*)d_out;

    int N = in_sizes[0] / CIN;
    const int threads = 256;
    int blocksN = (N + threads - 1) / threads;
    int cblocks = (N + 63) / 64;
    long total_vec = (long)N * COUT / 4;

    size_t a256 = 255;
    size_t recs_b     = (size_t)NWP * 8;                       // ~2.1 MB
    size_t off_skeys  = (recs_b + a256) & ~a256;
    size_t off_featbf = (off_skeys + (size_t)N * 4 + a256) & ~a256;
    size_t off_sorig  = (off_featbf + (size_t)(N + 1) * 16 + a256) & ~a256;
    size_t off_bcnt   = (off_sorig + (size_t)N * 4 + a256) & ~a256;
    size_t off_bbase  = (off_bcnt + 256 * 4 + a256) & ~a256;
    size_t off_wfrag  = (off_bbase + 256 * 4 + a256) & ~a256;
    size_t off_stats  = (off_wfrag + (size_t)(7 * 2 * 64) * 16 + a256) & ~a256;
    size_t off_scsh   = off_stats + (size_t)64 * 64 * 4;

    uint2* recs  = (uint2*)d_ws;
    int*   skeys = (int*)((char*)d_ws + off_skeys);
    uint4* featb = (uint4*)((char*)d_ws + off_featbf);
    int*   sorig = (int*)((char*)d_ws + off_sorig);
    int*   bcnt  = (int*)((char*)d_ws + off_bcnt);
    int*   bbase = (int*)((char*)d_ws + off_bbase);
    uint4* wfrag = (uint4*)((char*)d_ws + off_wfrag);
    float* stats = (float*)((char*)d_ws + off_stats);
    float* scsh  = (float*)((char*)d_ws + off_scsh);

    hipMemsetAsync(recs, 0, recs_b, stream);
    hipMemsetAsync(featb + N, 0, 16, stream);                  // zero row
    hipMemsetAsync(stats, 0, (size_t)64 * 64 * 4, stream);
    prep_wfrag<<<4, threads, 0, stream>>>(W, wfrag);
    build_bitmap_p<<<blocksN, threads, 0, stream>>>(coords, N, recs);
    bitmap_count_p<<<NBLKP, threads, 0, stream>>>(recs, bcnt);
    scan_small<<<1, threads, 0, stream>>>(bcnt, bbase, NBLKP);
    base_fill_p<<<NBLKP, threads, 0, stream>>>(recs, bbase);
    rank_scatter_p<<<blocksN, threads, 0, stream>>>(coords, feat, N, recs, sorig, skeys, featb);
    conv_mfma<<<cblocks, threads, 0, stream>>>(featb, skeys, sorig, wfrag, recs, N, out, stats);
    finalize_sliced<<<1, 64, 0, stream>>>(stats, gamma, beta, 1.0f / (float)N, scsh);
    norm_kernel<<<2048, threads, 0, stream>>>(out, total_vec, scsh);
}

// Round 11
// 229.587 us; speedup vs baseline: 1.0965x; 1.0535x over previous
//
#include <hip/hip_runtime.h>
#include <stdint.h>

#define GRIDX 200
#define P 202                                   // padded grid dim
#define PCELL (P * P * P)                       // 8,242,408
#define GUARD 100000
#define NBITS (PCELL + GUARD)
#define NWP ((NBITS + 31) / 32)                 // 260,701 words
#define K_INV (PCELL + 50000)                   // guaranteed-miss key (guard center)
#define CIN 6
#define COUT 32
#define NOFF 27
#define BN_EPS 1e-5f
#define WPB 1024
#define NBLKP ((NWP + WPB - 1) / WPB)           // 255 (<=256 for single-block scan)

typedef __attribute__((ext_vector_type(8))) short short8;
typedef __attribute__((ext_vector_type(4))) float f32x4;

// ---------------- helpers ----------------

__device__ __forceinline__ int xcd_swizzle(int b, int nwg) {
    int q = nwg >> 3, r = nwg & 7;
    int xcd = b & 7, idx = b >> 3;
    int base = (xcd < r) ? xcd * (q + 1) : r * (q + 1) + (xcd - r) * q;
    return base + idx;
}

__device__ __forceinline__ unsigned short f2bf(float f) {
    uint32_t u = __float_as_uint(f);
    return (unsigned short)((u + 0x7FFFu + ((u >> 16) & 1u)) >> 16);   // RNE
}
__device__ __forceinline__ uint32_t pack2(float a, float b) {
    return (uint32_t)f2bf(a) | ((uint32_t)f2bf(b) << 16);
}

// ---------------- padded bitmap rank structure (uint2 = {word, base}) ----------------

__global__ void build_bitmap_p(const int* __restrict__ coords, int N,
                               uint2* __restrict__ recs) {
    int i = blockIdx.x * blockDim.x + threadIdx.x;
    if (i >= N) return;
    int x = coords[3 * i], y = coords[3 * i + 1], z = coords[3 * i + 2];
    int key = ((x + 1) * P + (y + 1)) * P + (z + 1);
    atomicOr((unsigned int*)&recs[key >> 5], 1u << (key & 31));
}

__global__ __launch_bounds__(256)
void bitmap_count_p(const uint2* __restrict__ recs, int* __restrict__ bcnt) {
    __shared__ int tot[256];
    int b = blockIdx.x, t = threadIdx.x;
    int w0 = b * WPB + t * 4;
    int s = 0;
#pragma unroll
    for (int j = 0; j < 4; j++) {
        int w = w0 + j;
        if (w < NWP) s += __popc(recs[w].x);
    }
    tot[t] = s;
    __syncthreads();
    if (t < 128) tot[t] += tot[t + 128];
    __syncthreads();
    if (t < 64) {
        int v = tot[t] + tot[t + 64];
#pragma unroll
        for (int d = 32; d > 0; d >>= 1) v += __shfl_down(v, d);
        if (t == 0) bcnt[b] = v;
    }
}

// exclusive scan of n<=256 values, one block of 256 threads
__global__ void scan_small(const int* __restrict__ cnt, int* __restrict__ base, int n) {
    __shared__ int tot[256];
    int t = threadIdx.x;
    int v = (t < n) ? cnt[t] : 0;
    tot[t] = v;
    __syncthreads();
    for (int d = 1; d < 256; d <<= 1) {
        int u = (t >= d) ? tot[t - d] : 0;
        __syncthreads();
        tot[t] += u;
        __syncthreads();
    }
    if (t < n) base[t] = tot[t] - v;     // exclusive
}

__global__ __launch_bounds__(256)
void base_fill_p(uint2* __restrict__ recs, const int* __restrict__ bbase) {
    __shared__ int tot[256];
    int b = blockIdx.x, t = threadIdx.x;
    int w0 = b * WPB + t * 4;
    int p[4];
    int s = 0;
#pragma unroll
    for (int j = 0; j < 4; j++) {
        int w = w0 + j;
        p[j] = (w < NWP) ? __popc(recs[w].x) : 0;
        s += p[j];
    }
    tot[t] = s;
    __syncthreads();
    for (int d = 1; d < 256; d <<= 1) {
        int u = (t >= d) ? tot[t - d] : 0;
        __syncthreads();
        tot[t] += u;
        __syncthreads();
    }
    int run = bbase[b] + tot[t] - s;     // exclusive global rank of first word
#pragma unroll
    for (int j = 0; j < 4; j++) {
        int w = w0 + j;
        if (w < NWP) recs[w].y = (uint32_t)run;
        run += p[j];
    }
}

// ---------------- rank scatter: original order -> sorted order ----------------

__global__ __launch_bounds__(256)
void rank_scatter_p(const int* __restrict__ coords, const float* __restrict__ feat, int N,
                    const uint2* __restrict__ recs,
                    int* __restrict__ sorig, int* __restrict__ skeys,
                    uint4* __restrict__ feat_bf) {
    int i = blockIdx.x * blockDim.x + threadIdx.x;
    if (i >= N) return;
    int x = coords[3 * i], y = coords[3 * i + 1], z = coords[3 * i + 2];
    int key = ((x + 1) * P + (y + 1)) * P + (z + 1);
    uint2 rb = recs[key >> 5];
    int bit = key & 31;
    int r = (int)(rb.y + (uint32_t)__popc(rb.x & ((1u << bit) - 1u)));
    sorig[r] = i;
    skeys[r] = key;
    const float* fr = feat + (size_t)i * CIN;
    float2 a = *(const float2*)fr;
    float2 bb = *(const float2*)(fr + 2);
    float2 cc = *(const float2*)(fr + 4);
    uint4 u;
    u.x = pack2(a.x, a.y);
    u.y = pack2(bb.x, bb.y);
    u.z = pack2(cc.x, cc.y);
    u.w = 0u;
    feat_bf[r] = u;
}

// ---------------- W fragment prep (once) ----------------
// K-packing: k = koff*8 + ci (ci<6 real, ci=6,7 zero; koff>=27 zero).
// B-fragment (16x16x32 bf16): lane l holds B[k = ks*32+(l>>4)*8+b][col = nt*16+(l&15)]

__global__ void prep_wfrag(const float* __restrict__ W, uint4* __restrict__ wfrag) {
    int idx = blockIdx.x * blockDim.x + threadIdx.x;
    if (idx >= 7 * 2 * 64) return;
    int l = idx & 63;
    int nt = (idx >> 6) & 1;
    int ks = idx >> 7;
    int koff = ks * 4 + (l >> 4);
    int col = nt * 16 + (l & 15);
    unsigned short v[8];
#pragma unroll
    for (int ci = 0; ci < 8; ci++) {
        float f = 0.f;
        if (ci < CIN && koff < NOFF) f = W[(koff * CIN + ci) * COUT + col];
        v[ci] = f2bf(f);
    }
    uint4 u;
    u.x = (uint32_t)v[0] | ((uint32_t)v[1] << 16);
    u.y = (uint32_t)v[2] | ((uint32_t)v[3] << 16);
    u.z = (uint32_t)v[4] | ((uint32_t)v[5] << 16);
    u.w = (uint32_t)v[6] | ((uint32_t)v[7] << 16);
    wfrag[idx] = u;
}

// ---------------- conv: multi-site-block, predicated gathers, fused stats ----------------

__global__ __launch_bounds__(256, 4)
void conv_mfma(const uint4* __restrict__ feat_bf,
               const int* __restrict__ skeys,
               const int* __restrict__ sorig,
               const uint4* __restrict__ wfrag,
               const uint2* __restrict__ recs, int N, int nsb,
               float* __restrict__ out,
               float* __restrict__ stats_g) {
    __shared__ __align__(16) float Clds[64 * 36];    // 9216 B
    __shared__ float bstat[64];

    int tid = threadIdx.x;
    int w = tid >> 6, l = tid & 63;
    int col = l & 15;
    int rg = l >> 4;
    int kb = rg;

    if (tid < 64) bstat[tid] = 0.f;

    // B fragments: loaded ONCE per block (amortized over ~15 site-blocks)
    const short8* wf8 = (const short8*)wfrag;
    short8 bf0[7], bf1[7];
#pragma unroll
    for (int ks = 0; ks < 7; ks++) {
        bf0[ks] = wf8[(ks * 2 + 0) * 64 + l];
        bf1[ks] = wf8[(ks * 2 + 1) * 64 + l];
    }

    // key deltas: computed ONCE (koff = ks*4 + kb); pad slot handled via miss key
    int dlt[7];
    bool pad[7];
#pragma unroll
    for (int ks = 0; ks < 7; ks++) {
        int koff = ks * 4 + kb;
        pad[ks] = (koff >= NOFF);
        int t9 = koff / 9;
        int r9 = koff - t9 * 9;
        int t3 = r9 / 3;
        dlt[ks] = (t9 - 1) * (P * P) + (t3 - 1) * P + (r9 - t3 * 3 - 1);
    }

    const short8* fb8 = (const short8*)feat_bf;
    const uint4* fb16 = (const uint4*)feat_bf;

    // per-thread stats accumulators (raw, reduced once at the end)
    float as0 = 0.f, aq0 = 0.f, as1 = 0.f, aq1 = 0.f;

    for (int sb = blockIdx.x; sb < nsb; sb += gridDim.x) {
        int b = xcd_swizzle(sb, nsb);
        int bs = b * 64;
        int site = bs + w * 16 + col;
        int key = (site < N) ? skeys[site] : K_INV;

        // rank probes + PREDICATED gathers (miss lanes issue no address)
        short8 av[7];
#pragma unroll
        for (int ks = 0; ks < 7; ks++) {
            int nkey = pad[ks] ? K_INV : key + dlt[ks];
            uint2 rb = recs[nkey >> 5];
            int bit = nkey & 31;
            bool hit = (rb.x >> bit) & 1u;
            uint4 a4 = make_uint4(0u, 0u, 0u, 0u);
            if (hit) {
                int pos = (int)(rb.y + (uint32_t)__popc(rb.x & ((1u << bit) - 1u)));
                a4 = fb16[pos];
            }
            av[ks] = *(const short8*)&a4;
        }

        f32x4 acc0 = {0.f, 0.f, 0.f, 0.f};
        f32x4 acc1 = {0.f, 0.f, 0.f, 0.f};
#pragma unroll
        for (int ks = 0; ks < 7; ks++) {
            acc0 = __builtin_amdgcn_mfma_f32_16x16x32_bf16(av[ks], bf0[ks], acc0, 0, 0, 0);
            acc1 = __builtin_amdgcn_mfma_f32_16x16x32_bf16(av[ks], bf1[ks], acc1, 0, 0, 0);
        }

        // accumulate stats (invalid sites contribute exact zeros)
        as0 += acc0[0] + acc0[1] + acc0[2] + acc0[3];
        aq0 += acc0[0]*acc0[0] + acc0[1]*acc0[1] + acc0[2]*acc0[2] + acc0[3]*acc0[3];
        as1 += acc1[0] + acc1[1] + acc1[2] + acc1[3];
        aq1 += acc1[0]*acc1[0] + acc1[1]*acc1[1] + acc1[2]*acc1[2] + acc1[3]*acc1[3];

        __syncthreads();                 // prev iteration's Clds reads complete
#pragma unroll
        for (int r = 0; r < 4; r++) {
            int s = w * 16 + rg * 4 + r; // C/D map: col=lane&15, row=(lane>>4)*4+r
            Clds[s * 36 + col] = acc0[r];
            Clds[s * 36 + col + 16] = acc1[r];
        }
        __syncthreads();                 // Clds writes complete

        int st = tid >> 2;               // site-local 0..63
        int q = (tid & 3) * 2;           // chunk pair
        int sr = bs + st;
        if (sr < N) {
            float4* gp = (float4*)(out + (size_t)sorig[sr] * COUT + q * 4);
            gp[0] = *(const float4*)&Clds[st * 36 + q * 4];
            gp[1] = *(const float4*)&Clds[st * 36 + q * 4 + 4];
        }
    }

    // final stats reduction (once per block)
    as0 += __shfl_xor(as0, 16); as0 += __shfl_xor(as0, 32);
    aq0 += __shfl_xor(aq0, 16); aq0 += __shfl_xor(aq0, 32);
    as1 += __shfl_xor(as1, 16); as1 += __shfl_xor(as1, 32);
    aq1 += __shfl_xor(aq1, 16); aq1 += __shfl_xor(aq1, 32);
    __syncthreads();
    if (l < 16) {
        atomicAdd(&bstat[col], as0);
        atomicAdd(&bstat[16 + col], as1);
        atomicAdd(&bstat[32 + col], aq0);
        atomicAdd(&bstat[48 + col], aq1);
    }
    __syncthreads();
    if (tid < 64) {
        int slice = blockIdx.x & 63;
        atomicAdd(&stats_g[slice * 64 + tid], bstat[tid]);
    }
}

// ---------------- BN finalize / norm ----------------

__global__ void finalize_sliced(const float* __restrict__ stats_g,
                                const float* __restrict__ gamma,
                                const float* __restrict__ beta,
                                float invN, float* __restrict__ scsh) {
    int c = threadIdx.x;
    if (c < COUT) {
        float s = 0.f, q = 0.f;
        for (int sl = 0; sl < 64; sl++) {
            s += stats_g[sl * 64 + c];
            q += stats_g[sl * 64 + 32 + c];
        }
        float mean = s * invN;
        float var = q * invN - mean * mean;
        float sc = gamma[c] * rsqrtf(var + BN_EPS);
        scsh[c] = sc;
        scsh[COUT + c] = beta[c] - mean * sc;
    }
}

__global__ __launch_bounds__(256)
void norm_kernel(float* __restrict__ out, long total_vec,
                 const float* __restrict__ scaleshift) {
    __shared__ float sc[COUT], sh[COUT];
    for (int t = threadIdx.x; t < COUT; t += blockDim.x) {
        sc[t] = scaleshift[t];
        sh[t] = scaleshift[COUT + t];
    }
    __syncthreads();
    long stride = (long)gridDim.x * blockDim.x;
    float4* p = (float4*)out;
    for (long v = (long)blockIdx.x * blockDim.x + threadIdx.x; v < total_vec; v += stride) {
        int cbase = (int)(v & 7) * 4;
        float4 u = p[v];
        u.x = fmaxf(u.x * sc[cbase + 0] + sh[cbase + 0], 0.f);
        u.y = fmaxf(u.y * sc[cbase + 1] + sh[cbase + 1], 0.f);
        u.z = fmaxf(u.z * sc[cbase + 2] + sh[cbase + 2], 0.f);
        u.w = fmaxf(u.w * sc[cbase + 3] + sh[cbase + 3], 0.f);
        p[v] = u;
    }
}

// ---------------- launch ----------------

extern "C" void kernel_launch(void* const* d_in, const int* in_sizes, int n_in,
                              void* d_out, int out_size, void* d_ws, size_t ws_size,
                              hipStream_t stream) {
    const float* feat   = (const float*)d_in[0];
    const int*   coords = (const int*)d_in[1];
    const float* W      = (const float*)d_in[2];
    const float* gamma  = (const float*)d_in[3];
    const float* beta   = (const float*)d_in[4];
    float* out = (float*)d_out;

    int N = in_sizes[0] / CIN;
    const int threads = 256;
    int blocksN = (N + threads - 1) / threads;
    int nsb = (N + 63) / 64;
    int cblocks = 1024;                  // grid-stride over site-blocks
    long total_vec = (long)N * COUT / 4;

    size_t a256 = 255;
    size_t recs_b     = (size_t)NWP * 8;                       // ~2.1 MB
    size_t off_skeys  = (recs_b + a256) & ~a256;
    size_t off_featbf = (off_skeys + (size_t)N * 4 + a256) & ~a256;
    size_t off_sorig  = (off_featbf + (size_t)(N + 1) * 16 + a256) & ~a256;
    size_t off_bcnt   = (off_sorig + (size_t)N * 4 + a256) & ~a256;
    size_t off_bbase  = (off_bcnt + 256 * 4 + a256) & ~a256;
    size_t off_wfrag  = (off_bbase + 256 * 4 + a256) & ~a256;
    size_t off_stats  = (off_wfrag + (size_t)(7 * 2 * 64) * 16 + a256) & ~a256;
    size_t off_scsh   = off_stats + (size_t)64 * 64 * 4;

    uint2* recs  = (uint2*)d_ws;
    int*   skeys = (int*)((char*)d_ws + off_skeys);
    uint4* featb = (uint4*)((char*)d_ws + off_featbf);
    int*   sorig = (int*)((char*)d_ws + off_sorig);
    int*   bcnt  = (int*)((char*)d_ws + off_bcnt);
    int*   bbase = (int*)((char*)d_ws + off_bbase);
    uint4* wfrag = (uint4*)((char*)d_ws + off_wfrag);
    float* stats = (float*)((char*)d_ws + off_stats);
    float* scsh  = (float*)((char*)d_ws + off_scsh);

    hipMemsetAsync(recs, 0, recs_b, stream);
    hipMemsetAsync(featb + N, 0, 16, stream);                  // zero row (unused now, safety)
    hipMemsetAsync(stats, 0, (size_t)64 * 64 * 4, stream);
    prep_wfrag<<<4, threads, 0, stream>>>(W, wfrag);
    build_bitmap_p<<<blocksN, threads, 0, stream>>>(coords, N, recs);
    bitmap_count_p<<<NBLKP, threads, 0, stream>>>(recs, bcnt);
    scan_small<<<1, threads, 0, stream>>>(bcnt, bbase, NBLKP);
    base_fill_p<<<NBLKP, threads, 0, stream>>>(recs, bbase);
    rank_scatter_p<<<blocksN, threads, 0, stream>>>(coords, feat, N, recs, sorig, skeys, featb);
    conv_mfma<<<cblocks, threads, 0, stream>>>(featb, skeys, sorig, wfrag, recs, N, nsb, out, stats);
    finalize_sliced<<<1, 64, 0, stream>>>(stats, gamma, beta, 1.0f / (float)N, scsh);
    norm_kernel<<<2048, threads, 0, stream>>>(out, total_vec, scsh);
}